// Round 14
// baseline (504.852 us; speedup 1.0000x reference)
//
#include <hip/hip_runtime.h>
#include <hip/hip_bf16.h>
#include <cstdint>
#include <cstddef>

#define AS1 __attribute__((address_space(1)))
#define AS3 __attribute__((address_space(3)))

typedef __hip_bfloat16 bf16;
typedef float f32x4 __attribute__((ext_vector_type(4)));
typedef short bf16x8 __attribute__((ext_vector_type(8)));

#define B_     4
#define T_     2048
#define D_     1024
#define E_     8
#define H_     4096
#define NTOK   8192
#define CAP    1280
#define VOCAB_ 256

// ---- workspace layout (bytes) ----
static constexpr size_t OFF_PG    = 0;                 // 2 MB
static constexpr size_t OFF_Y     = 2097152;           // 32 MB (y; later ffn2 part0)
static constexpr size_t OFF_TOP   = 35651584;
static constexpr size_t OFF_GATE  = 35684352;
static constexpr size_t OFF_ENT   = 35717120;
static constexpr size_t OFF_CNT   = 35749888;
static constexpr size_t OFF_CKEPT = 35750144;
static constexpr size_t OFF_SLOT  = 35750400;
static constexpr size_t OFF_XE    = 35791360;          // 20 MB (Xe; later ffn2 part1)
static constexpr size_t OFF_HE    = 56762880;          // 80 MB (partials/pg_seq early, then He)
static constexpr size_t OFF_WT    = 140648960;         // 64 MB (W1t then W2t)
static constexpr size_t OFF_WHT   = 207757824;
static constexpr size_t OFF_OUTB  = 208282112;         // 16 MB

// d_out layout (floats)
#define LOGITS_OFF 0
#define NS_OFF     2097152
#define ENT_OFF    2101248
#define CNT_OFF    2101249

__device__ __forceinline__ void gll16(const void* g, void* l) {
  __builtin_amdgcn_global_load_lds((AS1 const void*)g, (AS3 void*)l, 16, 0, 0);
}
__device__ __forceinline__ unsigned short f2bu(float f) {
  bf16 h = __float2bfloat16(f);
  return __builtin_bit_cast(unsigned short, h);
}
__device__ __forceinline__ float bu2f(unsigned short u) {
  unsigned int x = ((unsigned int)u) << 16;
  return __builtin_bit_cast(float, x);
}
// tanh(z) = 1 - 2/(exp(2z)+1); ~1e-6 rel err
__device__ __forceinline__ float fast_tanh(float z) {
  float e2 = __expf(z + z);
  return fmaf(-2.f, __builtin_amdgcn_rcpf(e2 + 1.f), 1.f);
}

// ---------------- embproj split-K partial GEMM ----------------
__global__ __launch_bounds__(256) void slv_embproj_part(
    const float* __restrict__ emb, const float* __restrict__ Wp,
    const float* __restrict__ Wg,
    float* __restrict__ Ppart, float* __restrict__ Gpart) {
  __shared__ float embT[128][9];
  int rb = blockIdx.x, kc = blockIdx.y;
  int r0 = rb * 8, k0 = kc * 128;
  int tid = threadIdx.x;
  int c = tid * 4;
  {
    int i4 = tid * 4;
    int r = i4 >> 7, kb = i4 & 127;
    f32x4 v = *reinterpret_cast<const f32x4*>(emb + (size_t)(r0 + r) * D_ + k0 + kb);
    embT[kb + 0][r] = v.x; embT[kb + 1][r] = v.y;
    embT[kb + 2][r] = v.z; embT[kb + 3][r] = v.w;
  }
  __syncthreads();
  f32x4 aP[8] = {}, aG[8] = {};
  #pragma unroll 4
  for (int kk = 0; kk < 128; ++kk) {
    f32x4 wp = *reinterpret_cast<const f32x4*>(Wp + (size_t)(k0 + kk) * D_ + c);
    f32x4 wg = *reinterpret_cast<const f32x4*>(Wg + (size_t)(k0 + kk) * D_ + c);
    #pragma unroll
    for (int r = 0; r < 8; ++r) {
      float e = embT[kk][r];
      aP[r] += e * wp;
      aG[r] += e * wg;
    }
  }
  #pragma unroll
  for (int r = 0; r < 8; ++r) {
    size_t o = ((size_t)kc * 256 + r0 + r) * D_ + c;
    *reinterpret_cast<f32x4*>(Ppart + o) = aP[r];
    *reinterpret_cast<f32x4*>(Gpart + o) = aG[r];
  }
}

// reduce 8 k-partials, add bias, sigmoid for G, write interleaved PG float2
__global__ __launch_bounds__(256) void slv_embproj_reduce(
    const float* __restrict__ Ppart, const float* __restrict__ Gpart,
    const float* __restrict__ bp, const float* __restrict__ bg,
    float2* __restrict__ PG) {
  int i = blockIdx.x * 256 + threadIdx.x;
  int r = i >> 8;
  int c = (i & 255) * 4;
  f32x4 sp = {}, sg = {};
  #pragma unroll
  for (int kc = 0; kc < 8; ++kc) {
    size_t o = ((size_t)kc * 256 + r) * D_ + c;
    sp += *reinterpret_cast<const f32x4*>(Ppart + o);
    sg += *reinterpret_cast<const f32x4*>(Gpart + o);
  }
  sp += *reinterpret_cast<const f32x4*>(bp + c);
  sg += *reinterpret_cast<const f32x4*>(bg + c);
  f32x4 g;
  g.x = 1.f / (1.f + __expf(-sg.x));
  g.y = 1.f / (1.f + __expf(-sg.y));
  g.z = 1.f / (1.f + __expf(-sg.z));
  g.w = 1.f / (1.f + __expf(-sg.w));
  f32x4 st0 = { sp.x, g.x, sp.y, g.y };
  f32x4 st1 = { sp.z, g.z, sp.w, g.w };
  f32x4* dst = reinterpret_cast<f32x4*>(PG + (size_t)r * D_ + c);
  dst[0] = st0; dst[1] = st1;
}

// ---------------- gather PG rows per timestep ----------------
__global__ __launch_bounds__(256) void slv_gatherpg(
    const int* __restrict__ bytes, const float2* __restrict__ PG,
    float2* __restrict__ pg_seq) {
  int t0 = blockIdx.x * 16;
  __shared__ int bl[16];
  if (threadIdx.x < 16) bl[threadIdx.x] = bytes[t0 + threadIdx.x];
  __syncthreads();
  int c = threadIdx.x * 4;
  #pragma unroll 4
  for (int u = 0; u < 16; ++u) {
    const f32x4* src = (const f32x4*)(PG + (size_t)bl[u] * D_ + c);
    f32x4* dst = (f32x4*)(pg_seq + (size_t)(t0 + u) * D_ + c);
    f32x4 v0 = src[0], v1 = src[1];
    dst[0] = v0; dst[1] = v1;
  }
}

// ---------------- SSM scan (standalone; (64,1) bounds — round-10 lesson) ----------------
#define SU 16
__global__ __launch_bounds__(64, 1) void slv_scan(
    const float2* __restrict__ pg_seq,
    float* __restrict__ y, float* __restrict__ ns) {
  int b = blockIdx.x >> 4;
  int d = (blockIdx.x & 15) * 64 + threadIdx.x;
  const float2* pp = pg_seq + (size_t)b * T_ * D_ + d;
  float* yp = y + (size_t)b * T_ * D_ + d;
  float2 pA[SU], pB[SU];
  #pragma unroll
  for (int u = 0; u < SU; ++u) pA[u] = pp[(size_t)u * D_];
  float s = 0.f;
  for (int t0 = 0; t0 < T_; t0 += 2 * SU) {
    #pragma unroll
    for (int u = 0; u < SU; ++u) pB[u] = pp[(size_t)(t0 + SU + u) * D_];
    #pragma unroll
    for (int u = 0; u < SU; ++u) {
      s = fast_tanh(pA[u].x + s);
      yp[(size_t)(t0 + u) * D_] = pA[u].y * s;
    }
    if (t0 + 2 * SU < T_) {
      #pragma unroll
      for (int u = 0; u < SU; ++u) pA[u] = pp[(size_t)(t0 + 2 * SU + u) * D_];
    }
    #pragma unroll
    for (int u = 0; u < SU; ++u) {
      s = fast_tanh(pB[u].x + s);
      yp[(size_t)(t0 + SU + u) * D_] = pB[u].y * s;
    }
  }
  ns[b * D_ + d] = s;
}

// ---------------- transpose tile helper (fp32 -> bf16, 64x64) ----------------
__device__ __forceinline__ void transpose_tile(
    const float* __restrict__ in, bf16* __restrict__ out, int R, int C,
    int bx, int by, int bz, int tid) {
  __shared__ float tile[64][65];
  size_t mat = (size_t)bz * R * C;
  int c0 = bx * 64, r0 = by * 64;
  #pragma unroll
  for (int j = 0; j < 16; ++j) {
    int idx = j * 256 + tid; int r = idx >> 6, c = idx & 63;
    tile[r][c] = in[mat + (size_t)(r0 + r) * C + c0 + c];
  }
  __syncthreads();
  #pragma unroll
  for (int j = 0; j < 4; ++j) {
    int lin = j * 256 + tid;
    int cc = lin >> 4;
    int rr = (lin & 15) * 4;
    ushort4 v;
    v.x = f2bu(tile[rr + 0][cc]); v.y = f2bu(tile[rr + 1][cc]);
    v.z = f2bu(tile[rr + 2][cc]); v.w = f2bu(tile[rr + 3][cc]);
    *(ushort4*)((unsigned short*)out + mat + (size_t)(c0 + cc) * R + r0 + rr) = v;
  }
}

__global__ __launch_bounds__(256) void slv_transpose(
    const float* __restrict__ in, bf16* __restrict__ out, int R, int C) {
  transpose_tile(in, out, R, C, blockIdx.x, blockIdx.y, blockIdx.z, threadIdx.x);
}

// ---------------- router (no atomics — counts come from slv_capacity) ----------------
__global__ __launch_bounds__(256) void slv_router(
    const float* __restrict__ y, const float* __restrict__ Wr, const float* __restrict__ br,
    int* __restrict__ top, float* __restrict__ gate, float* __restrict__ entTok) {
  int wave = threadIdx.x >> 6, lane = threadIdx.x & 63;
  int tok = blockIdx.x * 4 + wave;
  const float* yr = y + (size_t)tok * D_;
  float acc[E_];
  #pragma unroll
  for (int e = 0; e < E_; ++e) acc[e] = 0.f;
  for (int i = 0; i < 16; ++i) {
    int d = i * 64 + lane;
    float v = yr[d];
    const float4* w = (const float4*)(Wr + d * E_);
    float4 w0 = w[0], w1 = w[1];
    acc[0] = fmaf(v, w0.x, acc[0]); acc[1] = fmaf(v, w0.y, acc[1]);
    acc[2] = fmaf(v, w0.z, acc[2]); acc[3] = fmaf(v, w0.w, acc[3]);
    acc[4] = fmaf(v, w1.x, acc[4]); acc[5] = fmaf(v, w1.y, acc[5]);
    acc[6] = fmaf(v, w1.z, acc[6]); acc[7] = fmaf(v, w1.w, acc[7]);
  }
  #pragma unroll
  for (int off = 32; off; off >>= 1)
    #pragma unroll
    for (int e = 0; e < E_; ++e) acc[e] += __shfl_xor(acc[e], off);
  if (lane == 0) {
    float l[E_], p[E_];
    float mx = -1e30f;
    #pragma unroll
    for (int e = 0; e < E_; ++e) { l[e] = acc[e] + br[e]; mx = fmaxf(mx, l[e]); }
    float sum = 0.f;
    #pragma unroll
    for (int e = 0; e < E_; ++e) { p[e] = expf(l[e] - mx); sum += p[e]; }
    float inv = 1.f / sum;
    int bestE = 0; float bestP = -1.f; float ent = 0.f;
    #pragma unroll
    for (int e = 0; e < E_; ++e) {
      float pe = p[e] * inv;
      ent += pe * logf(pe + 1e-9f);
      if (pe > bestP) { bestP = pe; bestE = e; }
    }
    top[tok] = bestE; gate[tok] = bestP; entTok[tok] = ent;
  }
}

// ---------------- capacity assignment (single block, shuffle-scan) ----------------
__global__ __launch_bounds__(256) void slv_capacity(
    const int* __restrict__ top, int* __restrict__ slotTok, int* __restrict__ cntKept,
    int* __restrict__ countsInt) {
  __shared__ unsigned char tops[NTOK];
  __shared__ unsigned int wt[4][4];
  int tid = threadIdx.x, lane = tid & 63, w = tid >> 6;
  for (int i = tid; i < NTOK; i += 256) tops[i] = (unsigned char)top[i];
  __syncthreads();
  unsigned int c0 = 0, c1 = 0, c2 = 0, c3 = 0;
  int n0 = tid * 32;
  for (int i = 0; i < 32; ++i) {
    int v = tops[n0 + i];
    unsigned inc = 1u << ((v & 1) << 4);
    int hi = v >> 1;
    if (hi == 0) c0 += inc;
    else if (hi == 1) c1 += inc;
    else if (hi == 2) c2 += inc;
    else c3 += inc;
  }
  unsigned int s0 = c0, s1 = c1, s2 = c2, s3 = c3;
  #pragma unroll
  for (int off = 1; off < 64; off <<= 1) {
    unsigned int t0 = (unsigned)__shfl_up((int)s0, off);
    unsigned int t1 = (unsigned)__shfl_up((int)s1, off);
    unsigned int t2 = (unsigned)__shfl_up((int)s2, off);
    unsigned int t3 = (unsigned)__shfl_up((int)s3, off);
    if (lane >= off) { s0 += t0; s1 += t1; s2 += t2; s3 += t3; }
  }
  if (lane == 63) { wt[w][0] = s0; wt[w][1] = s1; wt[w][2] = s2; wt[w][3] = s3; }
  __syncthreads();
  unsigned int p0 = 0, p1 = 0, p2 = 0, p3 = 0;
  for (int i = 0; i < w; ++i) { p0 += wt[i][0]; p1 += wt[i][1]; p2 += wt[i][2]; p3 += wt[i][3]; }
  unsigned int e0 = s0 - c0 + p0, e1 = s1 - c1 + p1, e2 = s2 - c2 + p2, e3 = s3 - c3 + p3;
  int base[E_];
  base[0] = e0 & 0xffff; base[1] = e0 >> 16;
  base[2] = e1 & 0xffff; base[3] = e1 >> 16;
  base[4] = e2 & 0xffff; base[5] = e2 >> 16;
  base[6] = e3 & 0xffff; base[7] = e3 >> 16;
  if (tid == 0) {
    unsigned int t0t = wt[0][0] + wt[1][0] + wt[2][0] + wt[3][0];
    unsigned int t1t = wt[0][1] + wt[1][1] + wt[2][1] + wt[3][1];
    unsigned int t2t = wt[0][2] + wt[1][2] + wt[2][2] + wt[3][2];
    unsigned int t3t = wt[0][3] + wt[1][3] + wt[2][3] + wt[3][3];
    int cnt[E_];
    cnt[0] = (int)(t0t & 0xffff); cnt[1] = (int)(t0t >> 16);
    cnt[2] = (int)(t1t & 0xffff); cnt[3] = (int)(t1t >> 16);
    cnt[4] = (int)(t2t & 0xffff); cnt[5] = (int)(t2t >> 16);
    cnt[6] = (int)(t3t & 0xffff); cnt[7] = (int)(t3t >> 16);
    #pragma unroll
    for (int e = 0; e < E_; ++e) {
      countsInt[e] = cnt[e];
      cntKept[e] = min(cnt[e], CAP);
    }
  }
  for (int i = 0; i < 32; ++i) {
    int n = n0 + i;
    int v = tops[n];
    #pragma unroll
    for (int e = 0; e < E_; ++e) {
      if (v == e) {
        int r = base[e]++;
        if (r < CAP) slotTok[e * CAP + r] = n;
      }
    }
  }
}

// ---------------- gather tokens into expert slots (bf16) ----------------
__global__ __launch_bounds__(256) void slv_gather(
    const float* __restrict__ y, const int* __restrict__ slotTok,
    const int* __restrict__ cntKept, unsigned short* __restrict__ Xe) {
  int slot = blockIdx.x;
  int e = slot / CAP, r = slot % CAP;
  int c4 = threadIdx.x * 4;
  ushort4 o;
  if (r < cntKept[e]) {
    int tok = slotTok[slot];
    float4 v = *(const float4*)(y + (size_t)tok * D_ + c4);
    o.x = f2bu(v.x); o.y = f2bu(v.y); o.z = f2bu(v.z); o.w = f2bu(v.w);
  } else {
    o.x = 0; o.y = 0; o.z = 0; o.w = 0;
  }
  *(ushort4*)(Xe + (size_t)slot * D_ + c4) = o;
}

// ---------------- legacy MFMA GEMM core (BM=BN=128, BK=64, 4 waves) — head ----------------
__device__ __forceinline__ void gemm_core(
    const char* ga, const char* gb, int K, bf16* As, bf16* Bs,
    f32x4 (&acc)[4][4], int wave, int lane, int wr, int wc) {
  const int Krow = K * 2;
  for (int ks = 0; ks < K; ks += 64) {
    #pragma unroll
    for (int rnd = 0; rnd < 4; ++rnd) {
      int chunk = rnd * 4 + wave;
      int o = chunk * 1024 + lane * 16;
      int row = o >> 7, col = o & 127;
      int scol = col ^ ((row & 7) << 4);
      size_t gofs = (size_t)row * Krow + (size_t)ks * 2 + scol;
      gll16(ga + gofs, (char*)As + chunk * 1024);
      gll16(gb + gofs, (char*)Bs + chunk * 1024);
    }
    __syncthreads();
    #pragma unroll
    for (int kk = 0; kk < 2; ++kk) {
      bf16x8 a[4], b[4];
      int koff = kk * 64 + ((lane >> 4) << 4);
      #pragma unroll
      for (int m = 0; m < 4; ++m) {
        int row = wr * 64 + m * 16 + (lane & 15);
        int sc = koff ^ ((row & 7) << 4);
        a[m] = *(const bf16x8*)((const char*)As + row * 128 + sc);
      }
      #pragma unroll
      for (int n = 0; n < 4; ++n) {
        int row = wc * 64 + n * 16 + (lane & 15);
        int sc = koff ^ ((row & 7) << 4);
        b[n] = *(const bf16x8*)((const char*)Bs + row * 128 + sc);
      }
      #pragma unroll
      for (int m = 0; m < 4; ++m)
        #pragma unroll
        for (int n = 0; n < 4; ++n)
          acc[m][n] = __builtin_amdgcn_mfma_f32_16x16x32_bf16(a[m], b[n], acc[m][n], 0, 0, 0);
    }
    __syncthreads();
  }
}

// ---------------- 128x256 / K-half=32 core, 3 rotating 24KB slots = 72KB LDS ------------
// 2 blocks/CU.  8 waves (2M x 4N), per-wave 64x64 = acc[4][4].  One barrier per
// half.  Pair-packed swizzle: (row,kb) -> 128*(row>>1) +
// ((64*(row&1)+kb) ^ (((row>>1)&7)<<4)); read addr composed OR-then-XOR over
// the full 7-bit remainder (round-8 lesson).
__device__ __forceinline__ void gemm_hp(
    const char* ga, const char* gb, size_t krow, size_t kbyte0, int NH,
    char* lds, int tid, int lane, int wr, int wc, f32x4 (&acc)[4][4]) {
  auto STG = [&](int h, int r) {
    int o = (r == 0) ? (tid * 16) : ((r - 1) * 8192 + tid * 16);
    int l = o >> 7, rem = o & 127;
    int rem2 = rem ^ ((l & 7) << 4);
    int row = 2 * l + (rem2 >> 6);
    int kb = rem2 & 63;
    const char* g = (r == 0) ? ga : gb;
    size_t gofs = (size_t)row * krow + kbyte0 + (size_t)h * 64 + kb;
    gll16(g + gofs, lds + (h % 3) * 24576 + ((r == 0) ? 0 : 8192) + o);
  };
  int lhalf = (lane & 15) >> 1;
  int aoff = (((lane & 1) << 6) | ((lane >> 4) << 4)) ^ (lhalf << 4);
  STG(0, 0); STG(0, 1); STG(0, 2);
  STG(1, 0); STG(1, 1); STG(1, 2);
  asm volatile("s_waitcnt vmcnt(3)" ::: "memory");   // slot 0 resident (own loads)
  __builtin_amdgcn_s_barrier();                      // ... for all waves
  for (int h = 0; h < NH; ++h) {
    const char* Ab = lds + (h % 3) * 24576;
    const char* Bb = Ab + 8192;
    bf16x8 a[4], b[4];
    #pragma unroll
    for (int m = 0; m < 4; ++m)
      a[m] = *(const bf16x8*)(Ab + 128 * (wr * 32 + m * 8 + lhalf) + aoff);
    #pragma unroll
    for (int n = 0; n < 4; ++n)
      b[n] = *(const bf16x8*)(Bb + 128 * (wc * 32 + n * 8 + lhalf) + aoff);
    if (h + 2 < NH) { STG(h + 2, 0); STG(h + 2, 1); STG(h + 2, 2); }
    if (h + 1 < NH) {
      if (h + 2 < NH) asm volatile("s_waitcnt vmcnt(3)" ::: "memory");  // drain h+1
      else            asm volatile("s_waitcnt vmcnt(0)" ::: "memory");
    }
    asm volatile("s_waitcnt lgkmcnt(0)" ::: "memory");
    __builtin_amdgcn_sched_barrier(0);
    __builtin_amdgcn_s_setprio(1);
    #pragma unroll
    for (int m = 0; m < 4; ++m)
      #pragma unroll
      for (int n = 0; n < 4; ++n)
        acc[m][n] = __builtin_amdgcn_mfma_f32_16x16x32_bf16(a[m], b[n], acc[m][n], 0, 0, 0);
    __builtin_amdgcn_s_setprio(0);
    __builtin_amdgcn_s_barrier();
  }
}

// ---------------- FFN1: He = gelu(Xe @ W1 + b1), 128x256 hp core ----------------
// XCD-aware 1-D grid (T1): bid = (nt*10 + mt)*8 + e  =>  XCD(bid%8) = e.
__global__ __launch_bounds__(512, 4) void slv_ffn1_hp(
    const bf16* __restrict__ Xe, const bf16* __restrict__ W1t, const float* __restrict__ b1,
    const int* __restrict__ cntKept, unsigned short* __restrict__ He) {
  int bid = blockIdx.x;                 // 1280
  int e = bid & 7;
  int tmp = bid >> 3;                   // 0..159 = nt*10 + mt
  int mt = tmp % 10;                    // 0..9
  int nt = tmp / 10;                    // 0..15
  if (mt * 128 >= cntKept[e]) return;
  extern __shared__ char lds[];
  int tid = threadIdx.x, wave = tid >> 6, lane = tid & 63;
  int wr = wave >> 2, wc = wave & 3;
  const char* ga = (const char*)(Xe + ((size_t)e * CAP + mt * 128) * D_);
  const char* gb = (const char*)(W1t + ((size_t)e * H_ + nt * 256) * D_);
  f32x4 acc[4][4] = {};
  gemm_hp(ga, gb, (size_t)D_ * 2, 0, D_ / 32, lds, tid, lane, wr, wc, acc);
  size_t slot0 = (size_t)e * CAP + mt * 128;
  int colb = nt * 256 + wc * 64;
  #pragma unroll
  for (int m = 0; m < 4; ++m) {
    int trow0 = wr * 64 + m * 16 + ((lane >> 4) << 2);
    #pragma unroll
    for (int n = 0; n < 4; ++n) {
      int col = colb + n * 16 + (lane & 15);
      float bias = b1[e * H_ + col];
      #pragma unroll
      for (int r = 0; r < 4; ++r) {
        float x = acc[m][n][r] + bias;
        float t = fast_tanh(0.7978845608028654f * (x + 0.044715f * x * x * x));
        float gel = 0.5f * x * (1.f + t);
        He[(slot0 + trow0 + r) * (size_t)H_ + col] = f2bu(gel);
      }
    }
  }
}

// ---------------- FFN2 split-K=2 partial: 128x256 hp core, bf16 partials ----------------
// XCD-aware 1-D grid: bid = (nt*10 + mt)*16 + ez, 640 blocks  =>  XCD = ez%8.
// ROUND-13 FIX: mt in 0..9 (CAP/128), nt in 0..3 (D/256) — previous decode had
// the ranges transposed (mt<=3 left slots 512..1279 poisoned -> NaN; nt<=15
// indexed W2t out of bounds).
__global__ __launch_bounds__(512, 4) void slv_ffn2_hp(
    const bf16* __restrict__ He, const bf16* __restrict__ W2t,
    const int* __restrict__ cntKept,
    unsigned short* __restrict__ part0, unsigned short* __restrict__ part1) {
  int bid = blockIdx.x;                 // 640
  int ez = bid & 15;
  int tmp = bid >> 4;                   // 0..39 = nt*10 + mt
  int mt = tmp % 10;                    // 0..9
  int nt = tmp / 10;                    // 0..3
  int e = ez >> 1, s = ez & 1;
  if (mt * 128 >= cntKept[e]) return;
  extern __shared__ char lds[];
  int tid = threadIdx.x, wave = tid >> 6, lane = tid & 63;
  int wr = wave >> 2, wc = wave & 3;
  const char* ga = (const char*)(He + ((size_t)e * CAP + mt * 128) * H_);
  const char* gb = (const char*)(W2t + ((size_t)e * D_ + nt * 256) * H_);
  f32x4 acc[4][4] = {};
  gemm_hp(ga, gb, (size_t)H_ * 2, (size_t)s * 2048 * 2, 2048 / 32,
          lds, tid, lane, wr, wc, acc);
  unsigned short* part = s ? part1 : part0;
  size_t slot0 = (size_t)e * CAP + mt * 128;
  int colb = nt * 256 + wc * 64;
  #pragma unroll
  for (int m = 0; m < 4; ++m) {
    int trow0 = wr * 64 + m * 16 + ((lane >> 4) << 2);
    #pragma unroll
    for (int n = 0; n < 4; ++n) {
      int col = colb + n * 16 + (lane & 15);
      #pragma unroll
      for (int r = 0; r < 4; ++r)
        part[(slot0 + trow0 + r) * (size_t)D_ + col] = f2bu(acc[m][n][r]);
    }
  }
}

// ---------------- FFN2 reduce: outb[tok] = (p0+p1+b2)*gate ----------------
__global__ __launch_bounds__(256) void slv_ffn2_reduce(
    const unsigned short* __restrict__ part0, const unsigned short* __restrict__ part1,
    const float* __restrict__ b2, const int* __restrict__ cntKept,
    const int* __restrict__ slotTok, const float* __restrict__ gate,
    unsigned short* __restrict__ outb) {
  int slot = blockIdx.x;
  int e = slot / CAP, r = slot % CAP;
  if (r >= cntKept[e]) return;
  int tok = slotTok[slot];
  float sc = gate[tok];
  int c4 = threadIdx.x * 4;
  ushort4 p0 = *(const ushort4*)(part0 + (size_t)slot * D_ + c4);
  ushort4 p1 = *(const ushort4*)(part1 + (size_t)slot * D_ + c4);
  const float4 bb = *(const float4*)(b2 + e * D_ + c4);
  ushort4 o;
  o.x = f2bu((bu2f(p0.x) + bu2f(p1.x) + bb.x) * sc);
  o.y = f2bu((bu2f(p0.y) + bu2f(p1.y) + bb.y) * sc);
  o.z = f2bu((bu2f(p0.z) + bu2f(p1.z) + bb.z) * sc);
  o.w = f2bu((bu2f(p0.w) + bu2f(p1.w) + bb.w) * sc);
  *(ushort4*)(outb + (size_t)tok * D_ + c4) = o;
}

// ---------------- head: logits = outb @ Wh + bh (fp32 out) ----------------
__global__ __launch_bounds__(256) void slv_head(
    const bf16* __restrict__ outb, const bf16* __restrict__ Wht, const float* __restrict__ bh,
    float* __restrict__ logits) {
  int nt = blockIdx.x, mt = blockIdx.y;    // (2,64)
  __shared__ __align__(16) bf16 As[128 * 64], Bs[128 * 64];
  int tid = threadIdx.x, wave = tid >> 6, lane = tid & 63;
  int wr = wave >> 1, wc = wave & 1;
  const char* ga = (const char*)(outb + (size_t)mt * 128 * D_);
  const char* gb = (const char*)(Wht + (size_t)nt * 128 * D_);
  f32x4 acc[4][4] = {};
  gemm_core(ga, gb, D_, As, Bs, acc, wave, lane, wr, wc);
  int colb = nt * 128 + wc * 64;
  #pragma unroll
  for (int m = 0; m < 4; ++m) {
    int trow0 = wr * 64 + m * 16 + ((lane >> 4) << 2);
    #pragma unroll
    for (int n = 0; n < 4; ++n) {
      int col = colb + n * 16 + (lane & 15);
      float bias = bh[col];
      #pragma unroll
      for (int r = 0; r < 4; ++r) {
        int row = mt * 128 + trow0 + r;
        logits[(size_t)row * VOCAB_ + col] = acc[m][n][r] + bias;
      }
    }
  }
}

// ---------------- finalize ----------------
__global__ __launch_bounds__(256) void slv_finalize(
    const float* __restrict__ entTok, const int* __restrict__ countsInt,
    float* __restrict__ out) {
  __shared__ float red[256];
  int tid = threadIdx.x;
  float s = 0.f;
  for (int i = tid; i < NTOK; i += 256) s += entTok[i];
  red[tid] = s;
  __syncthreads();
  for (int off = 128; off; off >>= 1) {
    if (tid < off) red[tid] += red[tid + off];
    __syncthreads();
  }
  if (tid == 0) out[ENT_OFF] = -red[0] / (float)NTOK;
  if (tid < E_) out[CNT_OFF + tid] = (float)countsInt[tid];
}

extern "C" void kernel_launch(void* const* d_in, const int* in_sizes, int n_in,
                              void* d_out, int out_size, void* d_ws, size_t ws_size,
                              hipStream_t stream) {
  (void)in_sizes; (void)n_in; (void)out_size; (void)ws_size;
  const int*   byte_seq = (const int*)d_in[0];
  const float* emb = (const float*)d_in[1];
  const float* Wp  = (const float*)d_in[2];
  const float* bp  = (const float*)d_in[3];
  const float* Wg  = (const float*)d_in[4];
  const float* bg  = (const float*)d_in[5];
  const float* Wr  = (const float*)d_in[6];
  const float* br  = (const float*)d_in[7];
  const float* W1  = (const float*)d_in[8];
  const float* b1  = (const float*)d_in[9];
  const float* W2  = (const float*)d_in[10];
  const float* b2  = (const float*)d_in[11];
  const float* Wh  = (const float*)d_in[12];
  const float* bh  = (const float*)d_in[13];
  float* out = (float*)d_out;

  char* ws = (char*)d_ws;
  float2* PG      = (float2*)(ws + OFF_PG);
  float* y        = (float*)(ws + OFF_Y);
  int*   top      = (int*)(ws + OFF_TOP);
  float* gate     = (float*)(ws + OFF_GATE);
  float* entTok   = (float*)(ws + OFF_ENT);
  int*   countsInt= (int*)(ws + OFF_CNT);
  int*   cntKept  = (int*)(ws + OFF_CKEPT);
  int*   slotTok  = (int*)(ws + OFF_SLOT);
  unsigned short* Xe  = (unsigned short*)(ws + OFF_XE);
  unsigned short* He  = (unsigned short*)(ws + OFF_HE);
  bf16*  Wt       = (bf16*)(ws + OFF_WT);
  bf16*  Wht      = (bf16*)(ws + OFF_WHT);
  unsigned short* outb = (unsigned short*)(ws + OFF_OUTB);
  float*  Ppart   = (float*)(ws + OFF_HE);
  float*  Gpart   = (float*)(ws + OFF_HE + 8388608);
  float2* pg_seq  = (float2*)(ws + OFF_HE);
  unsigned short* part0 = (unsigned short*)(ws + OFF_Y);
  unsigned short* part1 = (unsigned short*)(ws + OFF_XE);

  hipFuncSetAttribute(reinterpret_cast<const void*>(slv_ffn1_hp),
                      hipFuncAttributeMaxDynamicSharedMemorySize, 73728);
  hipFuncSetAttribute(reinterpret_cast<const void*>(slv_ffn2_hp),
                      hipFuncAttributeMaxDynamicSharedMemorySize, 73728);

  hipMemsetAsync(outb, 0, (size_t)NTOK * D_ * 2, stream);

  slv_embproj_part<<<dim3(32, 8), 256, 0, stream>>>(emb, Wp, Wg, Ppart, Gpart);
  slv_embproj_reduce<<<256, 256, 0, stream>>>(Ppart, Gpart, bp, bg, PG);
  slv_gatherpg<<<NTOK / 16, 256, 0, stream>>>(byte_seq, PG, pg_seq);
  slv_scan<<<64, 64, 0, stream>>>(pg_seq, y, out + NS_OFF);
  slv_router<<<NTOK / 4, 256, 0, stream>>>(y, Wr, br, top, gate, entTok);
  slv_capacity<<<1, 256, 0, stream>>>(top, slotTok, cntKept, countsInt);
  slv_gather<<<E_ * CAP, 256, 0, stream>>>(y, slotTok, cntKept, Xe);

  slv_transpose<<<dim3(4, 16, 1), 256, 0, stream>>>(Wh, Wht, 1024, 256);
  slv_transpose<<<dim3(64, 16, 8), 256, 0, stream>>>(W1, Wt, 1024, 4096);
  slv_ffn1_hp<<<1280, 512, 73728, stream>>>((const bf16*)Xe, Wt, b1, cntKept, He);
  slv_transpose<<<dim3(16, 64, 8), 256, 0, stream>>>(W2, Wt, 4096, 1024);
  slv_ffn2_hp<<<640, 512, 73728, stream>>>((const bf16*)He, Wt, cntKept, part0, part1);
  slv_ffn2_reduce<<<E_ * CAP, 256, 0, stream>>>(part0, part1, b2, cntKept, slotTok, gate, outb);
  slv_head<<<dim3(2, 64), 256, 0, stream>>>((const bf16*)outb, Wht, bh, out + LOGITS_OFF);
  slv_finalize<<<1, 256, 0, stream>>>(entTok, countsInt, out);
}

// Round 15
// 473.209 us; speedup vs baseline: 1.0669x; 1.0669x over previous
//
#include <hip/hip_runtime.h>
#include <hip/hip_bf16.h>
#include <cstdint>
#include <cstddef>

#define AS1 __attribute__((address_space(1)))
#define AS3 __attribute__((address_space(3)))

typedef __hip_bfloat16 bf16;
typedef float f32x4 __attribute__((ext_vector_type(4)));
typedef short bf16x8 __attribute__((ext_vector_type(8)));

#define B_     4
#define T_     2048
#define D_     1024
#define E_     8
#define H_     4096
#define NTOK   8192
#define CAP    1280
#define VOCAB_ 256

// ---- workspace layout (bytes) ----
static constexpr size_t OFF_PG    = 0;                 // 2 MB
static constexpr size_t OFF_Y     = 2097152;           // 32 MB (y; later ffn2 part0)
static constexpr size_t OFF_TOP   = 35651584;
static constexpr size_t OFF_GATE  = 35684352;
static constexpr size_t OFF_ENT   = 35717120;
static constexpr size_t OFF_CNT   = 35749888;
static constexpr size_t OFF_CKEPT = 35750144;
static constexpr size_t OFF_SLOT  = 35750400;
static constexpr size_t OFF_XE    = 35791360;          // 20 MB (Xe; later ffn2 part1)
static constexpr size_t OFF_HE    = 56762880;          // 80 MB (partials/pg_seq early, then He)
static constexpr size_t OFF_WT    = 140648960;         // 64 MB (W1t then W2t)
static constexpr size_t OFF_WHT   = 207757824;
static constexpr size_t OFF_OUTB  = 208282112;         // 16 MB

// d_out layout (floats)
#define LOGITS_OFF 0
#define NS_OFF     2097152
#define ENT_OFF    2101248
#define CNT_OFF    2101249

__device__ __forceinline__ void gll16(const void* g, void* l) {
  __builtin_amdgcn_global_load_lds((AS1 const void*)g, (AS3 void*)l, 16, 0, 0);
}
__device__ __forceinline__ unsigned short f2bu(float f) {
  bf16 h = __float2bfloat16(f);
  return __builtin_bit_cast(unsigned short, h);
}
__device__ __forceinline__ float bu2f(unsigned short u) {
  unsigned int x = ((unsigned int)u) << 16;
  return __builtin_bit_cast(float, x);
}
// tanh(z) = 1 - 2/(exp(2z)+1); ~1e-6 rel err
__device__ __forceinline__ float fast_tanh(float z) {
  float e2 = __expf(z + z);
  return fmaf(-2.f, __builtin_amdgcn_rcpf(e2 + 1.f), 1.f);
}

// ---------------- embproj split-K partial GEMM ----------------
__global__ __launch_bounds__(256) void slv_embproj_part(
    const float* __restrict__ emb, const float* __restrict__ Wp,
    const float* __restrict__ Wg,
    float* __restrict__ Ppart, float* __restrict__ Gpart) {
  __shared__ float embT[128][9];
  int rb = blockIdx.x, kc = blockIdx.y;
  int r0 = rb * 8, k0 = kc * 128;
  int tid = threadIdx.x;
  int c = tid * 4;
  {
    int i4 = tid * 4;
    int r = i4 >> 7, kb = i4 & 127;
    f32x4 v = *reinterpret_cast<const f32x4*>(emb + (size_t)(r0 + r) * D_ + k0 + kb);
    embT[kb + 0][r] = v.x; embT[kb + 1][r] = v.y;
    embT[kb + 2][r] = v.z; embT[kb + 3][r] = v.w;
  }
  __syncthreads();
  f32x4 aP[8] = {}, aG[8] = {};
  #pragma unroll 4
  for (int kk = 0; kk < 128; ++kk) {
    f32x4 wp = *reinterpret_cast<const f32x4*>(Wp + (size_t)(k0 + kk) * D_ + c);
    f32x4 wg = *reinterpret_cast<const f32x4*>(Wg + (size_t)(k0 + kk) * D_ + c);
    #pragma unroll
    for (int r = 0; r < 8; ++r) {
      float e = embT[kk][r];
      aP[r] += e * wp;
      aG[r] += e * wg;
    }
  }
  #pragma unroll
  for (int r = 0; r < 8; ++r) {
    size_t o = ((size_t)kc * 256 + r0 + r) * D_ + c;
    *reinterpret_cast<f32x4*>(Ppart + o) = aP[r];
    *reinterpret_cast<f32x4*>(Gpart + o) = aG[r];
  }
}

// reduce 8 k-partials, add bias, sigmoid for G, write interleaved PG float2
__global__ __launch_bounds__(256) void slv_embproj_reduce(
    const float* __restrict__ Ppart, const float* __restrict__ Gpart,
    const float* __restrict__ bp, const float* __restrict__ bg,
    float2* __restrict__ PG) {
  int i = blockIdx.x * 256 + threadIdx.x;
  int r = i >> 8;
  int c = (i & 255) * 4;
  f32x4 sp = {}, sg = {};
  #pragma unroll
  for (int kc = 0; kc < 8; ++kc) {
    size_t o = ((size_t)kc * 256 + r) * D_ + c;
    sp += *reinterpret_cast<const f32x4*>(Ppart + o);
    sg += *reinterpret_cast<const f32x4*>(Gpart + o);
  }
  sp += *reinterpret_cast<const f32x4*>(bp + c);
  sg += *reinterpret_cast<const f32x4*>(bg + c);
  f32x4 g;
  g.x = 1.f / (1.f + __expf(-sg.x));
  g.y = 1.f / (1.f + __expf(-sg.y));
  g.z = 1.f / (1.f + __expf(-sg.z));
  g.w = 1.f / (1.f + __expf(-sg.w));
  f32x4 st0 = { sp.x, g.x, sp.y, g.y };
  f32x4 st1 = { sp.z, g.z, sp.w, g.w };
  f32x4* dst = reinterpret_cast<f32x4*>(PG + (size_t)r * D_ + c);
  dst[0] = st0; dst[1] = st1;
}

// ---------------- gather PG rows per timestep ----------------
__global__ __launch_bounds__(256) void slv_gatherpg(
    const int* __restrict__ bytes, const float2* __restrict__ PG,
    float2* __restrict__ pg_seq) {
  int t0 = blockIdx.x * 16;
  __shared__ int bl[16];
  if (threadIdx.x < 16) bl[threadIdx.x] = bytes[t0 + threadIdx.x];
  __syncthreads();
  int c = threadIdx.x * 4;
  #pragma unroll 4
  for (int u = 0; u < 16; ++u) {
    const f32x4* src = (const f32x4*)(PG + (size_t)bl[u] * D_ + c);
    f32x4* dst = (f32x4*)(pg_seq + (size_t)(t0 + u) * D_ + c);
    f32x4 v0 = src[0], v1 = src[1];
    dst[0] = v0; dst[1] = v1;
  }
}

// ---------------- SSM scan (standalone; (64,1) bounds — round-10 lesson) ----------------
#define SU 16
__global__ __launch_bounds__(64, 1) void slv_scan(
    const float2* __restrict__ pg_seq,
    float* __restrict__ y, float* __restrict__ ns) {
  int b = blockIdx.x >> 4;
  int d = (blockIdx.x & 15) * 64 + threadIdx.x;
  const float2* pp = pg_seq + (size_t)b * T_ * D_ + d;
  float* yp = y + (size_t)b * T_ * D_ + d;
  float2 pA[SU], pB[SU];
  #pragma unroll
  for (int u = 0; u < SU; ++u) pA[u] = pp[(size_t)u * D_];
  float s = 0.f;
  for (int t0 = 0; t0 < T_; t0 += 2 * SU) {
    #pragma unroll
    for (int u = 0; u < SU; ++u) pB[u] = pp[(size_t)(t0 + SU + u) * D_];
    #pragma unroll
    for (int u = 0; u < SU; ++u) {
      s = fast_tanh(pA[u].x + s);
      yp[(size_t)(t0 + u) * D_] = pA[u].y * s;
    }
    if (t0 + 2 * SU < T_) {
      #pragma unroll
      for (int u = 0; u < SU; ++u) pA[u] = pp[(size_t)(t0 + 2 * SU + u) * D_];
    }
    #pragma unroll
    for (int u = 0; u < SU; ++u) {
      s = fast_tanh(pB[u].x + s);
      yp[(size_t)(t0 + SU + u) * D_] = pB[u].y * s;
    }
  }
  ns[b * D_ + d] = s;
}

// ---------------- transpose tile helper (fp32 -> bf16, 64x64) ----------------
__device__ __forceinline__ void transpose_tile(
    const float* __restrict__ in, bf16* __restrict__ out, int R, int C,
    int bx, int by, int bz, int tid) {
  __shared__ float tile[64][65];
  size_t mat = (size_t)bz * R * C;
  int c0 = bx * 64, r0 = by * 64;
  #pragma unroll
  for (int j = 0; j < 16; ++j) {
    int idx = j * 256 + tid; int r = idx >> 6, c = idx & 63;
    tile[r][c] = in[mat + (size_t)(r0 + r) * C + c0 + c];
  }
  __syncthreads();
  #pragma unroll
  for (int j = 0; j < 4; ++j) {
    int lin = j * 256 + tid;
    int cc = lin >> 4;
    int rr = (lin & 15) * 4;
    ushort4 v;
    v.x = f2bu(tile[rr + 0][cc]); v.y = f2bu(tile[rr + 1][cc]);
    v.z = f2bu(tile[rr + 2][cc]); v.w = f2bu(tile[rr + 3][cc]);
    *(ushort4*)((unsigned short*)out + mat + (size_t)(c0 + cc) * R + r0 + rr) = v;
  }
}

__global__ __launch_bounds__(256) void slv_transpose(
    const float* __restrict__ in, bf16* __restrict__ out, int R, int C) {
  transpose_tile(in, out, R, C, blockIdx.x, blockIdx.y, blockIdx.z, threadIdx.x);
}

// ---------------- router (no atomics — counts come from slv_capacity) ----------------
__global__ __launch_bounds__(256) void slv_router(
    const float* __restrict__ y, const float* __restrict__ Wr, const float* __restrict__ br,
    int* __restrict__ top, float* __restrict__ gate, float* __restrict__ entTok) {
  int wave = threadIdx.x >> 6, lane = threadIdx.x & 63;
  int tok = blockIdx.x * 4 + wave;
  const float* yr = y + (size_t)tok * D_;
  float acc[E_];
  #pragma unroll
  for (int e = 0; e < E_; ++e) acc[e] = 0.f;
  for (int i = 0; i < 16; ++i) {
    int d = i * 64 + lane;
    float v = yr[d];
    const float4* w = (const float4*)(Wr + d * E_);
    float4 w0 = w[0], w1 = w[1];
    acc[0] = fmaf(v, w0.x, acc[0]); acc[1] = fmaf(v, w0.y, acc[1]);
    acc[2] = fmaf(v, w0.z, acc[2]); acc[3] = fmaf(v, w0.w, acc[3]);
    acc[4] = fmaf(v, w1.x, acc[4]); acc[5] = fmaf(v, w1.y, acc[5]);
    acc[6] = fmaf(v, w1.z, acc[6]); acc[7] = fmaf(v, w1.w, acc[7]);
  }
  #pragma unroll
  for (int off = 32; off; off >>= 1)
    #pragma unroll
    for (int e = 0; e < E_; ++e) acc[e] += __shfl_xor(acc[e], off);
  if (lane == 0) {
    float l[E_], p[E_];
    float mx = -1e30f;
    #pragma unroll
    for (int e = 0; e < E_; ++e) { l[e] = acc[e] + br[e]; mx = fmaxf(mx, l[e]); }
    float sum = 0.f;
    #pragma unroll
    for (int e = 0; e < E_; ++e) { p[e] = expf(l[e] - mx); sum += p[e]; }
    float inv = 1.f / sum;
    int bestE = 0; float bestP = -1.f; float ent = 0.f;
    #pragma unroll
    for (int e = 0; e < E_; ++e) {
      float pe = p[e] * inv;
      ent += pe * logf(pe + 1e-9f);
      if (pe > bestP) { bestP = pe; bestE = e; }
    }
    top[tok] = bestE; gate[tok] = bestP; entTok[tok] = ent;
  }
}

// ---------------- capacity assignment (single block, shuffle-scan) ----------------
__global__ __launch_bounds__(256) void slv_capacity(
    const int* __restrict__ top, int* __restrict__ slotTok, int* __restrict__ cntKept,
    int* __restrict__ countsInt) {
  __shared__ unsigned char tops[NTOK];
  __shared__ unsigned int wt[4][4];
  int tid = threadIdx.x, lane = tid & 63, w = tid >> 6;
  for (int i = tid; i < NTOK; i += 256) tops[i] = (unsigned char)top[i];
  __syncthreads();
  unsigned int c0 = 0, c1 = 0, c2 = 0, c3 = 0;
  int n0 = tid * 32;
  for (int i = 0; i < 32; ++i) {
    int v = tops[n0 + i];
    unsigned inc = 1u << ((v & 1) << 4);
    int hi = v >> 1;
    if (hi == 0) c0 += inc;
    else if (hi == 1) c1 += inc;
    else if (hi == 2) c2 += inc;
    else c3 += inc;
  }
  unsigned int s0 = c0, s1 = c1, s2 = c2, s3 = c3;
  #pragma unroll
  for (int off = 1; off < 64; off <<= 1) {
    unsigned int t0 = (unsigned)__shfl_up((int)s0, off);
    unsigned int t1 = (unsigned)__shfl_up((int)s1, off);
    unsigned int t2 = (unsigned)__shfl_up((int)s2, off);
    unsigned int t3 = (unsigned)__shfl_up((int)s3, off);
    if (lane >= off) { s0 += t0; s1 += t1; s2 += t2; s3 += t3; }
  }
  if (lane == 63) { wt[w][0] = s0; wt[w][1] = s1; wt[w][2] = s2; wt[w][3] = s3; }
  __syncthreads();
  unsigned int p0 = 0, p1 = 0, p2 = 0, p3 = 0;
  for (int i = 0; i < w; ++i) { p0 += wt[i][0]; p1 += wt[i][1]; p2 += wt[i][2]; p3 += wt[i][3]; }
  unsigned int e0 = s0 - c0 + p0, e1 = s1 - c1 + p1, e2 = s2 - c2 + p2, e3 = s3 - c3 + p3;
  int base[E_];
  base[0] = e0 & 0xffff; base[1] = e0 >> 16;
  base[2] = e1 & 0xffff; base[3] = e1 >> 16;
  base[4] = e2 & 0xffff; base[5] = e2 >> 16;
  base[6] = e3 & 0xffff; base[7] = e3 >> 16;
  if (tid == 0) {
    unsigned int t0t = wt[0][0] + wt[1][0] + wt[2][0] + wt[3][0];
    unsigned int t1t = wt[0][1] + wt[1][1] + wt[2][1] + wt[3][1];
    unsigned int t2t = wt[0][2] + wt[1][2] + wt[2][2] + wt[3][2];
    unsigned int t3t = wt[0][3] + wt[1][3] + wt[2][3] + wt[3][3];
    int cnt[E_];
    cnt[0] = (int)(t0t & 0xffff); cnt[1] = (int)(t0t >> 16);
    cnt[2] = (int)(t1t & 0xffff); cnt[3] = (int)(t1t >> 16);
    cnt[4] = (int)(t2t & 0xffff); cnt[5] = (int)(t2t >> 16);
    cnt[6] = (int)(t3t & 0xffff); cnt[7] = (int)(t3t >> 16);
    #pragma unroll
    for (int e = 0; e < E_; ++e) {
      countsInt[e] = cnt[e];
      cntKept[e] = min(cnt[e], CAP);
    }
  }
  for (int i = 0; i < 32; ++i) {
    int n = n0 + i;
    int v = tops[n];
    #pragma unroll
    for (int e = 0; e < E_; ++e) {
      if (v == e) {
        int r = base[e]++;
        if (r < CAP) slotTok[e * CAP + r] = n;
      }
    }
  }
}

// ---------------- gather tokens into expert slots (bf16) ----------------
__global__ __launch_bounds__(256) void slv_gather(
    const float* __restrict__ y, const int* __restrict__ slotTok,
    const int* __restrict__ cntKept, unsigned short* __restrict__ Xe) {
  int slot = blockIdx.x;
  int e = slot / CAP, r = slot % CAP;
  int c4 = threadIdx.x * 4;
  ushort4 o;
  if (r < cntKept[e]) {
    int tok = slotTok[slot];
    float4 v = *(const float4*)(y + (size_t)tok * D_ + c4);
    o.x = f2bu(v.x); o.y = f2bu(v.y); o.z = f2bu(v.z); o.w = f2bu(v.w);
  } else {
    o.x = 0; o.y = 0; o.z = 0; o.w = 0;
  }
  *(ushort4*)(Xe + (size_t)slot * D_ + c4) = o;
}

// ---------------- legacy MFMA GEMM core (BM=BN=128, BK=64, 4 waves) — head ----------------
__device__ __forceinline__ void gemm_core(
    const char* ga, const char* gb, int K, bf16* As, bf16* Bs,
    f32x4 (&acc)[4][4], int wave, int lane, int wr, int wc) {
  const int Krow = K * 2;
  for (int ks = 0; ks < K; ks += 64) {
    #pragma unroll
    for (int rnd = 0; rnd < 4; ++rnd) {
      int chunk = rnd * 4 + wave;
      int o = chunk * 1024 + lane * 16;
      int row = o >> 7, col = o & 127;
      int scol = col ^ ((row & 7) << 4);
      size_t gofs = (size_t)row * Krow + (size_t)ks * 2 + scol;
      gll16(ga + gofs, (char*)As + chunk * 1024);
      gll16(gb + gofs, (char*)Bs + chunk * 1024);
    }
    __syncthreads();
    #pragma unroll
    for (int kk = 0; kk < 2; ++kk) {
      bf16x8 a[4], b[4];
      int koff = kk * 64 + ((lane >> 4) << 4);
      #pragma unroll
      for (int m = 0; m < 4; ++m) {
        int row = wr * 64 + m * 16 + (lane & 15);
        int sc = koff ^ ((row & 7) << 4);
        a[m] = *(const bf16x8*)((const char*)As + row * 128 + sc);
      }
      #pragma unroll
      for (int n = 0; n < 4; ++n) {
        int row = wc * 64 + n * 16 + (lane & 15);
        int sc = koff ^ ((row & 7) << 4);
        b[n] = *(const bf16x8*)((const char*)Bs + row * 128 + sc);
      }
      #pragma unroll
      for (int m = 0; m < 4; ++m)
        #pragma unroll
        for (int n = 0; n < 4; ++n)
          acc[m][n] = __builtin_amdgcn_mfma_f32_16x16x32_bf16(a[m], b[n], acc[m][n], 0, 0, 0);
    }
    __syncthreads();
  }
}

// ---------------- 128x256 / K-half=32 core, 3 rotating 24KB slots = 72KB LDS ------------
// 2 blocks/CU.  8 waves (2M x 4N), per-wave 64x64 = acc[4][4].  One barrier per
// half.  3 slots is the MINIMAL counted-vmcnt structure: with 2 slots, other
// waves' gll16 completion into the next slot could only be guaranteed by a
// vmcnt(0) drain before the barrier (round-14 analysis).  Pair-packed swizzle:
// (row,kb) -> 128*(row>>1) + ((64*(row&1)+kb) ^ (((row>>1)&7)<<4)); read addr
// composed OR-then-XOR over the full 7-bit remainder (round-8 lesson).
__device__ __forceinline__ void gemm_hp(
    const char* ga, const char* gb, size_t krow, size_t kbyte0, int NH,
    char* lds, int tid, int lane, int wr, int wc, f32x4 (&acc)[4][4]) {
  auto STG = [&](int h, int r) {
    int o = (r == 0) ? (tid * 16) : ((r - 1) * 8192 + tid * 16);
    int l = o >> 7, rem = o & 127;
    int rem2 = rem ^ ((l & 7) << 4);
    int row = 2 * l + (rem2 >> 6);
    int kb = rem2 & 63;
    const char* g = (r == 0) ? ga : gb;
    size_t gofs = (size_t)row * krow + kbyte0 + (size_t)h * 64 + kb;
    gll16(g + gofs, lds + (h % 3) * 24576 + ((r == 0) ? 0 : 8192) + o);
  };
  int lhalf = (lane & 15) >> 1;
  int aoff = (((lane & 1) << 6) | ((lane >> 4) << 4)) ^ (lhalf << 4);
  STG(0, 0); STG(0, 1); STG(0, 2);
  STG(1, 0); STG(1, 1); STG(1, 2);
  asm volatile("s_waitcnt vmcnt(3)" ::: "memory");   // slot 0 resident (own loads)
  __builtin_amdgcn_s_barrier();                      // ... for all waves
  for (int h = 0; h < NH; ++h) {
    const char* Ab = lds + (h % 3) * 24576;
    const char* Bb = Ab + 8192;
    bf16x8 a[4], b[4];
    #pragma unroll
    for (int m = 0; m < 4; ++m)
      a[m] = *(const bf16x8*)(Ab + 128 * (wr * 32 + m * 8 + lhalf) + aoff);
    #pragma unroll
    for (int n = 0; n < 4; ++n)
      b[n] = *(const bf16x8*)(Bb + 128 * (wc * 32 + n * 8 + lhalf) + aoff);
    if (h + 2 < NH) { STG(h + 2, 0); STG(h + 2, 1); STG(h + 2, 2); }
    if (h + 1 < NH) {
      if (h + 2 < NH) asm volatile("s_waitcnt vmcnt(3)" ::: "memory");  // drain h+1
      else            asm volatile("s_waitcnt vmcnt(0)" ::: "memory");
    }
    asm volatile("s_waitcnt lgkmcnt(0)" ::: "memory");
    __builtin_amdgcn_sched_barrier(0);
    __builtin_amdgcn_s_setprio(1);
    #pragma unroll
    for (int m = 0; m < 4; ++m)
      #pragma unroll
      for (int n = 0; n < 4; ++n)
        acc[m][n] = __builtin_amdgcn_mfma_f32_16x16x32_bf16(a[m], b[n], acc[m][n], 0, 0, 0);
    __builtin_amdgcn_s_setprio(0);
    __builtin_amdgcn_s_barrier();
  }
}

// ---------------- FFN1: He = gelu(Xe @ W1 + b1), 128x256 hp core ----------------
// Linear dim3 grid (round-14 lesson: expert-pinned XCD swizzle converted
// per-expert load imbalance into per-XCD imbalance, 90->107 µs despite
// FETCH dropping 94->54 MB; linear dispatch spreads it evenly).
__global__ __launch_bounds__(512, 4) void slv_ffn1_hp(
    const bf16* __restrict__ Xe, const bf16* __restrict__ W1t, const float* __restrict__ b1,
    const int* __restrict__ cntKept, unsigned short* __restrict__ He) {
  int e = blockIdx.z, mt = blockIdx.y, nt = blockIdx.x;   // (16,10,8)
  if (mt * 128 >= cntKept[e]) return;
  extern __shared__ char lds[];
  int tid = threadIdx.x, wave = tid >> 6, lane = tid & 63;
  int wr = wave >> 2, wc = wave & 3;
  const char* ga = (const char*)(Xe + ((size_t)e * CAP + mt * 128) * D_);
  const char* gb = (const char*)(W1t + ((size_t)e * H_ + nt * 256) * D_);
  f32x4 acc[4][4] = {};
  gemm_hp(ga, gb, (size_t)D_ * 2, 0, D_ / 32, lds, tid, lane, wr, wc, acc);
  size_t slot0 = (size_t)e * CAP + mt * 128;
  int colb = nt * 256 + wc * 64;
  #pragma unroll
  for (int m = 0; m < 4; ++m) {
    int trow0 = wr * 64 + m * 16 + ((lane >> 4) << 2);
    #pragma unroll
    for (int n = 0; n < 4; ++n) {
      int col = colb + n * 16 + (lane & 15);
      float bias = b1[e * H_ + col];
      #pragma unroll
      for (int r = 0; r < 4; ++r) {
        float x = acc[m][n][r] + bias;
        float t = fast_tanh(0.7978845608028654f * (x + 0.044715f * x * x * x));
        float gel = 0.5f * x * (1.f + t);
        He[(slot0 + trow0 + r) * (size_t)H_ + col] = f2bu(gel);
      }
    }
  }
}

// ---------------- FFN2 split-K=2 partial: 128x256 hp core, bf16 partials ----------------
__global__ __launch_bounds__(512, 4) void slv_ffn2_hp(
    const bf16* __restrict__ He, const bf16* __restrict__ W2t,
    const int* __restrict__ cntKept,
    unsigned short* __restrict__ part0, unsigned short* __restrict__ part1) {
  int ez = blockIdx.z;                 // e*2 + s
  int e = ez >> 1, s = ez & 1;
  int mt = blockIdx.y, nt = blockIdx.x;   // (4,10,16)
  if (mt * 128 >= cntKept[e]) return;
  extern __shared__ char lds[];
  int tid = threadIdx.x, wave = tid >> 6, lane = tid & 63;
  int wr = wave >> 2, wc = wave & 3;
  const char* ga = (const char*)(He + ((size_t)e * CAP + mt * 128) * H_);
  const char* gb = (const char*)(W2t + ((size_t)e * D_ + nt * 256) * H_);
  f32x4 acc[4][4] = {};
  gemm_hp(ga, gb, (size_t)H_ * 2, (size_t)s * 2048 * 2, 2048 / 32,
          lds, tid, lane, wr, wc, acc);
  unsigned short* part = s ? part1 : part0;
  size_t slot0 = (size_t)e * CAP + mt * 128;
  int colb = nt * 256 + wc * 64;
  #pragma unroll
  for (int m = 0; m < 4; ++m) {
    int trow0 = wr * 64 + m * 16 + ((lane >> 4) << 2);
    #pragma unroll
    for (int n = 0; n < 4; ++n) {
      int col = colb + n * 16 + (lane & 15);
      #pragma unroll
      for (int r = 0; r < 4; ++r)
        part[(slot0 + trow0 + r) * (size_t)D_ + col] = f2bu(acc[m][n][r]);
    }
  }
}

// ---------------- FFN2 reduce: outb[tok] = (p0+p1+b2)*gate ----------------
__global__ __launch_bounds__(256) void slv_ffn2_reduce(
    const unsigned short* __restrict__ part0, const unsigned short* __restrict__ part1,
    const float* __restrict__ b2, const int* __restrict__ cntKept,
    const int* __restrict__ slotTok, const float* __restrict__ gate,
    unsigned short* __restrict__ outb) {
  int slot = blockIdx.x;
  int e = slot / CAP, r = slot % CAP;
  if (r >= cntKept[e]) return;
  int tok = slotTok[slot];
  float sc = gate[tok];
  int c4 = threadIdx.x * 4;
  ushort4 p0 = *(const ushort4*)(part0 + (size_t)slot * D_ + c4);
  ushort4 p1 = *(const ushort4*)(part1 + (size_t)slot * D_ + c4);
  const float4 bb = *(const float4*)(b2 + e * D_ + c4);
  ushort4 o;
  o.x = f2bu((bu2f(p0.x) + bu2f(p1.x) + bb.x) * sc);
  o.y = f2bu((bu2f(p0.y) + bu2f(p1.y) + bb.y) * sc);
  o.z = f2bu((bu2f(p0.z) + bu2f(p1.z) + bb.z) * sc);
  o.w = f2bu((bu2f(p0.w) + bu2f(p1.w) + bb.w) * sc);
  *(ushort4*)(outb + (size_t)tok * D_ + c4) = o;
}

// ---------------- head: logits = outb @ Wh + bh (fp32 out) ----------------
__global__ __launch_bounds__(256) void slv_head(
    const bf16* __restrict__ outb, const bf16* __restrict__ Wht, const float* __restrict__ bh,
    float* __restrict__ logits) {
  int nt = blockIdx.x, mt = blockIdx.y;    // (2,64)
  __shared__ __align__(16) bf16 As[128 * 64], Bs[128 * 64];
  int tid = threadIdx.x, wave = tid >> 6, lane = tid & 63;
  int wr = wave >> 1, wc = wave & 1;
  const char* ga = (const char*)(outb + (size_t)mt * 128 * D_);
  const char* gb = (const char*)(Wht + (size_t)nt * 128 * D_);
  f32x4 acc[4][4] = {};
  gemm_core(ga, gb, D_, As, Bs, acc, wave, lane, wr, wc);
  int colb = nt * 128 + wc * 64;
  #pragma unroll
  for (int m = 0; m < 4; ++m) {
    int trow0 = wr * 64 + m * 16 + ((lane >> 4) << 2);
    #pragma unroll
    for (int n = 0; n < 4; ++n) {
      int col = colb + n * 16 + (lane & 15);
      float bias = bh[col];
      #pragma unroll
      for (int r = 0; r < 4; ++r) {
        int row = mt * 128 + trow0 + r;
        logits[(size_t)row * VOCAB_ + col] = acc[m][n][r] + bias;
      }
    }
  }
}

// ---------------- finalize ----------------
__global__ __launch_bounds__(256) void slv_finalize(
    const float* __restrict__ entTok, const int* __restrict__ countsInt,
    float* __restrict__ out) {
  __shared__ float red[256];
  int tid = threadIdx.x;
  float s = 0.f;
  for (int i = tid; i < NTOK; i += 256) s += entTok[i];
  red[tid] = s;
  __syncthreads();
  for (int off = 128; off; off >>= 1) {
    if (tid < off) red[tid] += red[tid + off];
    __syncthreads();
  }
  if (tid == 0) out[ENT_OFF] = -red[0] / (float)NTOK;
  if (tid < E_) out[CNT_OFF + tid] = (float)countsInt[tid];
}

extern "C" void kernel_launch(void* const* d_in, const int* in_sizes, int n_in,
                              void* d_out, int out_size, void* d_ws, size_t ws_size,
                              hipStream_t stream) {
  (void)in_sizes; (void)n_in; (void)out_size; (void)ws_size;
  const int*   byte_seq = (const int*)d_in[0];
  const float* emb = (const float*)d_in[1];
  const float* Wp  = (const float*)d_in[2];
  const float* bp  = (const float*)d_in[3];
  const float* Wg  = (const float*)d_in[4];
  const float* bg  = (const float*)d_in[5];
  const float* Wr  = (const float*)d_in[6];
  const float* br  = (const float*)d_in[7];
  const float* W1  = (const float*)d_in[8];
  const float* b1  = (const float*)d_in[9];
  const float* W2  = (const float*)d_in[10];
  const float* b2  = (const float*)d_in[11];
  const float* Wh  = (const float*)d_in[12];
  const float* bh  = (const float*)d_in[13];
  float* out = (float*)d_out;

  char* ws = (char*)d_ws;
  float2* PG      = (float2*)(ws + OFF_PG);
  float* y        = (float*)(ws + OFF_Y);
  int*   top      = (int*)(ws + OFF_TOP);
  float* gate     = (float*)(ws + OFF_GATE);
  float* entTok   = (float*)(ws + OFF_ENT);
  int*   countsInt= (int*)(ws + OFF_CNT);
  int*   cntKept  = (int*)(ws + OFF_CKEPT);
  int*   slotTok  = (int*)(ws + OFF_SLOT);
  unsigned short* Xe  = (unsigned short*)(ws + OFF_XE);
  unsigned short* He  = (unsigned short*)(ws + OFF_HE);
  bf16*  Wt       = (bf16*)(ws + OFF_WT);
  bf16*  Wht      = (bf16*)(ws + OFF_WHT);
  unsigned short* outb = (unsigned short*)(ws + OFF_OUTB);
  float*  Ppart   = (float*)(ws + OFF_HE);
  float*  Gpart   = (float*)(ws + OFF_HE + 8388608);
  float2* pg_seq  = (float2*)(ws + OFF_HE);
  unsigned short* part0 = (unsigned short*)(ws + OFF_Y);
  unsigned short* part1 = (unsigned short*)(ws + OFF_XE);

  hipFuncSetAttribute(reinterpret_cast<const void*>(slv_ffn1_hp),
                      hipFuncAttributeMaxDynamicSharedMemorySize, 73728);
  hipFuncSetAttribute(reinterpret_cast<const void*>(slv_ffn2_hp),
                      hipFuncAttributeMaxDynamicSharedMemorySize, 73728);

  hipMemsetAsync(outb, 0, (size_t)NTOK * D_ * 2, stream);

  slv_embproj_part<<<dim3(32, 8), 256, 0, stream>>>(emb, Wp, Wg, Ppart, Gpart);
  slv_embproj_reduce<<<256, 256, 0, stream>>>(Ppart, Gpart, bp, bg, PG);
  slv_gatherpg<<<NTOK / 16, 256, 0, stream>>>(byte_seq, PG, pg_seq);
  slv_scan<<<64, 64, 0, stream>>>(pg_seq, y, out + NS_OFF);
  slv_router<<<NTOK / 4, 256, 0, stream>>>(y, Wr, br, top, gate, entTok);
  slv_capacity<<<1, 256, 0, stream>>>(top, slotTok, cntKept, countsInt);
  slv_gather<<<E_ * CAP, 256, 0, stream>>>(y, slotTok, cntKept, Xe);

  slv_transpose<<<dim3(4, 16, 1), 256, 0, stream>>>(Wh, Wht, 1024, 256);
  slv_transpose<<<dim3(64, 16, 8), 256, 0, stream>>>(W1, Wt, 1024, 4096);
  slv_ffn1_hp<<<dim3(16, 10, 8), 512, 73728, stream>>>((const bf16*)Xe, Wt, b1, cntKept, He);
  slv_transpose<<<dim3(16, 64, 8), 256, 0, stream>>>(W2, Wt, 4096, 1024);
  slv_ffn2_hp<<<dim3(4, 10, 16), 512, 73728, stream>>>((const bf16*)He, Wt, cntKept, part0, part1);
  slv_ffn2_reduce<<<E_ * CAP, 256, 0, stream>>>(part0, part1, b2, cntKept, slotTok, gate, outb);
  slv_head<<<dim3(2, 64), 256, 0, stream>>>((const bf16*)outb, Wht, bh, out + LOGITS_OFF);
  slv_finalize<<<1, 256, 0, stream>>>(entTok, countsInt, out);
}